// Round 16
// baseline (501.046 us; speedup 1.0000x reference)
//
#include <hip/hip_runtime.h>

#define N_FACES 50000
#define N_EDGES 800000
#define NB      16
#define HID     256
#define NOUT    512
#define SCAN_B  1024
#define SCAN_NB ((N_FACES + SCAN_B - 1) / SCAN_B)
#define NT      (N_FACES / 16)   // 3125 MFMA node-tiles (exact)

typedef __attribute__((ext_vector_type(8))) short short8v;
typedef __attribute__((ext_vector_type(4))) float float4v;
union U8 { uint4 u; short8v s; };

// ---------- wave helpers ----------
__device__ __forceinline__ float wave_sum(float v) {
#pragma unroll
  for (int o = 32; o; o >>= 1) v += __shfl_xor(v, o, 64);
  return v;
}

// ---------- order-preserving float<->uint encoding (for atomicMax) ----------
__device__ __forceinline__ unsigned enc_ord(float v) {
  unsigned b = __float_as_uint(v);
  return (b & 0x80000000u) ? ~b : (b | 0x80000000u);
}
__device__ __forceinline__ float dec_ord(unsigned e) {
  unsigned b = (e & 0x80000000u) ? (e ^ 0x80000000u) : ~e;
  return __uint_as_float(b);
}

// RNE float->bf16 (finite inputs)
__device__ __forceinline__ unsigned f2bf(float x) {
  unsigned u = __float_as_uint(x);
  return (u + 0x7fffu + ((u >> 16) & 1u)) >> 16;
}
__device__ __forceinline__ float bf_lo(unsigned u) { return __uint_as_float(u << 16); }
__device__ __forceinline__ float bf_hi(unsigned u) { return __uint_as_float(u & 0xffff0000u); }

// packed-bf16 dot2: d = a.lo*b.lo + a.hi*b.hi + c  (HW v_dot2_f32_bf16 when available)
#if __has_builtin(__builtin_amdgcn_fdot2_f32_bf16)
typedef __attribute__((ext_vector_type(2))) __bf16 bf16x2v;
__device__ __forceinline__ float dot2bf(unsigned a, unsigned b, float c) {
  union { unsigned u; bf16x2v v; } ua, ub;
  ua.u = a; ub.u = b;
  return __builtin_amdgcn_fdot2_f32_bf16(ua.v, ub.v, c, false);
}
#else
__device__ __forceinline__ float dot2bf(unsigned a, unsigned b, float c) {
  return fmaf(bf_lo(a), bf_lo(b), fmaf(bf_hi(a), bf_hi(b), c));
}
#endif

// ---------- CSR build ----------
__global__ void k_hist(const int* __restrict__ dst, int* __restrict__ cnt) {
  int e = blockIdx.x * blockDim.x + threadIdx.x;
  if (e < N_EDGES) atomicAdd(&cnt[dst[e]], 1);
}

__global__ void k_scan1(const int* __restrict__ cnt, int* __restrict__ bsum) {
  __shared__ int sh[SCAN_B];
  int i = blockIdx.x * SCAN_B + threadIdx.x;
  sh[threadIdx.x] = (i < N_FACES) ? cnt[i] : 0;
  __syncthreads();
  for (int off = SCAN_B / 2; off; off >>= 1) {
    if (threadIdx.x < off) sh[threadIdx.x] += sh[threadIdx.x + off];
    __syncthreads();
  }
  if (threadIdx.x == 0) bsum[blockIdx.x] = sh[0];
}

__global__ void k_scan2(int* __restrict__ bsum) {  // nb <= 64, one wave
  int t = threadIdx.x;
  int v = (t < SCAN_NB) ? bsum[t] : 0;
  int inc = v;
#pragma unroll
  for (int off = 1; off < 64; off <<= 1) {
    int u = __shfl_up(inc, off, 64);
    if (t >= off) inc += u;
  }
  if (t < SCAN_NB) bsum[t] = inc - v;  // exclusive
}

__global__ void k_scan3(const int* __restrict__ cnt, const int* __restrict__ bsum,
                        int* __restrict__ row_ptr) {
  __shared__ int sh[SCAN_B];
  int i = blockIdx.x * SCAN_B + threadIdx.x;
  int v = (i < N_FACES) ? cnt[i] : 0;
  sh[threadIdx.x] = v;
  __syncthreads();
  for (int off = 1; off < SCAN_B; off <<= 1) {
    int x = (threadIdx.x >= off) ? sh[threadIdx.x - off] : 0;
    __syncthreads();
    sh[threadIdx.x] += x;
    __syncthreads();
  }
  if (i < N_FACES) row_ptr[i] = bsum[blockIdx.x] + sh[threadIdx.x] - v;
  if (i == 0) row_ptr[N_FACES] = N_EDGES;
}

// ---------- degree counting-sort -> nperm (LDS-preaggregated, low contention) ----------
__global__ void k_dhist(const int* __restrict__ cnt, int* __restrict__ dbin) {
  __shared__ int lh[64];
  int t = threadIdx.x;
  if (t < 64) lh[t] = 0;
  __syncthreads();
  int n = blockIdx.x * blockDim.x + t;
  if (n < N_FACES) atomicAdd(&lh[min(cnt[n], 63)], 1);
  __syncthreads();
  if (t < 64 && lh[t] > 0) atomicAdd(&dbin[t], lh[t]);
}
__global__ void k_dscan(int* __restrict__ dbin) {  // 64 threads, one wave
  int t = threadIdx.x;
  int v = dbin[t];
  int inc = v;
#pragma unroll
  for (int off = 1; off < 64; off <<= 1) {
    int u = __shfl_up(inc, off, 64);
    if (t >= off) inc += u;
  }
  dbin[t] = inc - v;  // exclusive base; reused as fill counter
}
__global__ void k_dscatter(const int* __restrict__ cnt, int* __restrict__ dbin,
                           int* __restrict__ nperm) {
  __shared__ int lh[64];
  __shared__ int lbase[64];
  int t = threadIdx.x;
  if (t < 64) lh[t] = 0;
  __syncthreads();
  int n = blockIdx.x * blockDim.x + t;
  int b = 0, lrank = 0;
  if (n < N_FACES) {
    b = min(cnt[n], 63);
    lrank = atomicAdd(&lh[b], 1);  // LDS atomic: fast intra-block rank
  }
  __syncthreads();
  if (t < 64 && lh[t] > 0) lbase[t] = atomicAdd(&dbin[t], lh[t]);  // 1 global atomic per bin per block
  __syncthreads();
  if (n < N_FACES) nperm[lbase[b] + lrank] = n;
}

// ---------- scatter: stats + rec16 in EDGE order (coalesced); scattered 4B eid/csr_src ----------
__global__ void k_scatter(const int* __restrict__ dst, const int* __restrict__ src,
                          const float* __restrict__ xe, const int* __restrict__ row_ptr,
                          const float* __restrict__ eW, const float* __restrict__ eB,
                          int* __restrict__ fill, uint4* __restrict__ rec16,
                          int* __restrict__ csr_src, int* __restrict__ eid) {
  __shared__ float sw[6][HID];
  __shared__ float sb[HID];
  int t = threadIdx.x;
  for (int i = t; i < 6 * HID; i += 256) sw[i / HID][i % HID] = eW[i];
  for (int i = t; i < HID; i += 256) sb[i] = eB[i];
  __syncthreads();

  int e = blockIdx.x * 64 + (t >> 2);   // grid sized exactly: 12500 blocks
  int seg = t & 3;
  unsigned zb[6];
  float z[6];
#pragma unroll
  for (int k = 0; k < 6; ++k) {
    zb[k] = f2bf(xe[(size_t)e * 6 + k]);
    z[k] = __uint_as_float(zb[k] << 16);   // stats from bf16-rounded z (consistent)
  }
  if (seg == 0) {
    int d = dst[e];
    int p = atomicAdd(&fill[d], 1);
    int pos = row_ptr[d] + p;
    csr_src[pos] = src[e];   // scattered 4B (L2-absorbable)
    eid[pos] = e;            // scattered 4B (L2-absorbable)
  }

  float s1 = 0.f, s2 = 0.f;
  int cbase = seg * 64;
  int rot = 4 * seg;  // rotate start so the 4 segs hit distinct banks (4i+4s mod 32)
#pragma unroll 4
  for (int ii = 0; ii < 16; ++ii) {
    int c = cbase + ((4 * ii + rot) & 63);
    float4 w4 = *reinterpret_cast<const float4*>(&sb[c]);
#pragma unroll
    for (int k = 0; k < 6; ++k) {
      float4 m4 = *reinterpret_cast<const float4*>(&sw[k][c]);
      w4.x = fmaf(z[k], m4.x, w4.x); w4.y = fmaf(z[k], m4.y, w4.y);
      w4.z = fmaf(z[k], m4.z, w4.z); w4.w = fmaf(z[k], m4.w, w4.w);
    }
    w4.x = fmaxf(w4.x, 0.f); w4.y = fmaxf(w4.y, 0.f);
    w4.z = fmaxf(w4.z, 0.f); w4.w = fmaxf(w4.w, 0.f);
    s1 += (w4.x + w4.y) + (w4.z + w4.w);
    s2 += (w4.x * w4.x + w4.y * w4.y) + (w4.z * w4.z + w4.w * w4.w);
  }
  s1 += __shfl_xor(s1, 1, 64); s1 += __shfl_xor(s1, 2, 64);
  s2 += __shfl_xor(s2, 1, 64); s2 += __shfl_xor(s2, 2, 64);
  if (seg == 0) {
    float mu = s1 * (1.f / HID);
    float rs = rsqrtf(fmaxf(s2 * (1.f / HID) - mu * mu, 0.f) + 1e-5f);
    rec16[e] = make_uint4(zb[0] | (zb[1] << 16), zb[2] | (zb[3] << 16),
                          zb[4] | (zb[5] << 16), f2bf(mu) | (f2bf(rs) << 16));  // coalesced
  }
}

// ---------- encoders + mean aggregation (chunk-of-2 edges via eid; dot2 bf16; folded LN) ----------
__global__ void k_encode(const float* __restrict__ xf, const uint4* __restrict__ rec16,
                         const float* __restrict__ fW, const float* __restrict__ fB,
                         const float* __restrict__ fG, const float* __restrict__ fBe,
                         const float* __restrict__ eW, const float* __restrict__ eB,
                         const float* __restrict__ eG, const float* __restrict__ eBe,
                         const int* __restrict__ row_ptr, const int* __restrict__ nperm,
                         const int* __restrict__ eid,
                         float* __restrict__ h, unsigned* __restrict__ hbd) {
  int lane = threadIdx.x & 63;
  int n = nperm[blockIdx.x * 4 + (threadIdx.x >> 6)];

  // face encoder
  float x[7];
#pragma unroll
  for (int k = 0; k < 7; ++k) x[k] = xf[n * 7 + k];
  float y[4];
#pragma unroll
  for (int j = 0; j < 4; ++j) {
    int c = lane + 64 * j;
    float a = fB[c];
#pragma unroll
    for (int k = 0; k < 7; ++k) a += x[k] * fW[k * HID + c];
    y[j] = fmaxf(a, 0.f);
  }
  float s = y[0] + y[1] + y[2] + y[3];
  float s2 = y[0] * y[0] + y[1] * y[1] + y[2] * y[2] + y[3] * y[3];
  s = wave_sum(s); s2 = wave_sum(s2);
  float mu = s * (1.f / HID);
  float rs = rsqrtf(fmaxf(s2 * (1.f / HID) - mu * mu, 0.f) + 1e-5f);
  float hv[4];
#pragma unroll
  for (int j = 0; j < 4; ++j) {
    int c = lane + 64 * j;
    hv[j] = (y[j] - mu) * rs * fG[c] + fBe[c];
  }

  // hoist edge-encoder params; pack weights as bf16 k-pairs for dot2
  unsigned ewp[3][4];
  float eb[4], eg[4], ebe[4];
#pragma unroll
  for (int j = 0; j < 4; ++j) {
    int c = lane + 64 * j;
    eb[j] = eB[c]; eg[j] = eG[c]; ebe[j] = eBe[c];
#pragma unroll
    for (int kk = 0; kk < 3; ++kk)
      ewp[kk][j] = f2bf(eW[(2 * kk) * HID + c]) | (f2bf(eW[(2 * kk + 1) * HID + c]) << 16);
  }

  int e0 = row_ptr[n], e1 = row_ptr[n + 1];
  // folded LN: acc[j] = Σ relu(a)·rs ; smu = Σ μ·rs ; apply eg/ebe once at end
  float acc[4] = {0.f, 0.f, 0.f, 0.f};
  float smu = 0.f;
  int t = e0;
  // chunk-of-2: two independent eid->rec16 chains per iteration
  for (; t + 2 <= e1; t += 2) {
    int ea = eid[t], eb2 = eid[t + 1];
    uint4 cu = rec16[ea];
    uint4 cv = rec16[eb2];
    float emu0 = bf_lo(cu.w), ers0 = bf_hi(cu.w);
    float emu1 = bf_lo(cv.w), ers1 = bf_hi(cv.w);
    smu = fmaf(emu0, ers0, smu);
    smu = fmaf(emu1, ers1, smu);
#pragma unroll
    for (int j = 0; j < 4; ++j) {
      float a = dot2bf(cu.x, ewp[0][j], eb[j]);
      a = dot2bf(cu.y, ewp[1][j], a);
      a = dot2bf(cu.z, ewp[2][j], a);
      a = fmaxf(a, 0.f);
      acc[j] = fmaf(a, ers0, acc[j]);
      float b = dot2bf(cv.x, ewp[0][j], eb[j]);
      b = dot2bf(cv.y, ewp[1][j], b);
      b = dot2bf(cv.z, ewp[2][j], b);
      b = fmaxf(b, 0.f);
      acc[j] = fmaf(b, ers1, acc[j]);
    }
  }
  for (; t < e1; ++t) {
    uint4 cu = rec16[eid[t]];
    float emu0 = bf_lo(cu.w), ers0 = bf_hi(cu.w);
    smu = fmaf(emu0, ers0, smu);
#pragma unroll
    for (int j = 0; j < 4; ++j) {
      float a = dot2bf(cu.x, ewp[0][j], eb[j]);
      a = dot2bf(cu.y, ewp[1][j], a);
      a = dot2bf(cu.z, ewp[2][j], a);
      a = fmaxf(a, 0.f);
      acc[j] = fmaf(a, ers0, acc[j]);
    }
  }
  int cntE = e1 - e0;
  float inv = (cntE > 0) ? 1.f / (float)cntE : 0.f;
  float hval[4];
#pragma unroll
  for (int j = 0; j < 4; ++j) {
    float add = (cntE > 0) ? inv * eg[j] * (acc[j] - smu) + ebe[j] : 0.f;
    hval[j] = hv[j] + add;
    h[(size_t)n * HID + lane + 64 * j] = hval[j];
  }
  // packed bf16 h: dword idx = global_col/2; lane l owns cols l+64j, partner l^1
#pragma unroll
  for (int j = 0; j < 4; ++j) {
    float other = __shfl_xor(hval[j], 1, 64);
    if (!(lane & 1))
      hbd[(size_t)n * 128 + 32 * j + (lane >> 1)] = f2bf(hval[j]) | (f2bf(other) << 16);
  }
}

// ---------- pack W (fp32 [K][256]) into MFMA B-fragment layout (bf16) ----------
__global__ void k_packW(const float* __restrict__ W, uint4* __restrict__ Wp) {
  int i = blockIdx.x * 256 + threadIdx.x;  // 16ct * 8ks * 64lane = 8192
  int lane = i & 63, ks = (i >> 6) & 7, ct = i >> 9;
  int kbase = ks * 32 + (lane >> 4) * 8;
  int col = ct * 16 + (lane & 15);
  unsigned d[4];
#pragma unroll
  for (int r = 0; r < 4; ++r) {
    unsigned lo = f2bf(W[(size_t)(kbase + 2 * r) * HID + col]);
    unsigned hi = f2bf(W[(size_t)(kbase + 2 * r + 1) * HID + col]);
    d[r] = lo | (hi << 16);
  }
  Wp[i] = make_uint4(d[0], d[1], d[2], d[3]);
}

// ---------- MFMA GEMM: f=h@W (bf16), fused el/er + fb-layout write ----------
__global__ void k_gemm_mfma(const unsigned* __restrict__ hbd, const uint4* __restrict__ Wp,
                            const float* __restrict__ al, const float* __restrict__ ar,
                            unsigned* __restrict__ fb, float* __restrict__ el,
                            float* __restrict__ er) {
  int tile = blockIdx.x * 4 + (threadIdx.x >> 6);
  if (tile >= NT) return;
  int lane = threadIdx.x & 63;
  int c = lane & 15;   // A-row / B,D-col within tile
  int kg = lane >> 4;  // k-group
  int n0 = tile * 16;

  uint4 afrag[8];
#pragma unroll
  for (int ks = 0; ks < 8; ++ks)
    afrag[ks] = *reinterpret_cast<const uint4*>(hbd + (size_t)(n0 + c) * 128 + ks * 16 + kg * 4);

  float4v acc[16];
#pragma unroll
  for (int ct = 0; ct < 16; ++ct) acc[ct] = (float4v){0.f, 0.f, 0.f, 0.f};
#pragma unroll
  for (int ct = 0; ct < 16; ++ct) {
#pragma unroll
    for (int ks = 0; ks < 8; ++ks) {
      U8 a, b;
      a.u = afrag[ks];
      b.u = Wp[(ct * 8 + ks) * 64 + lane];
      acc[ct] = __builtin_amdgcn_mfma_f32_16x16x32_bf16(a.s, b.s, acc[ct], 0, 0, 0);
    }
  }

  // fb write (k_gat layout: dword = global_col/2): pack pair via shfl_xor(1)
#pragma unroll
  for (int ct = 0; ct < 16; ++ct) {
#pragma unroll
    for (int reg = 0; reg < 4; ++reg) {
      float v = acc[ct][reg];
      float vo = __shfl_xor(v, 1, 64);
      if (!(lane & 1)) {
        int nd = n0 + kg * 4 + reg;
        fb[(size_t)nd * 128 + ct * 8 + (c >> 1)] = f2bf(v) | (f2bf(vo) << 16);
      }
    }
  }

  // el/er: reduce over 16 cols per tile-col-group; head = ct>>2
  float alr[16], arr[16];
#pragma unroll
  for (int ct = 0; ct < 16; ++ct) {
    alr[ct] = al[ct * 16 + c];
    arr[ct] = ar[ct * 16 + c];
  }
#pragma unroll
  for (int hd = 0; hd < 4; ++hd) {
#pragma unroll
    for (int reg = 0; reg < 4; ++reg) {
      float pl = 0.f, pr = 0.f;
#pragma unroll
      for (int q = 0; q < 4; ++q) {
        int ct = hd * 4 + q;
        pl = fmaf(acc[ct][reg], alr[ct], pl);
        pr = fmaf(acc[ct][reg], arr[ct], pr);
      }
#pragma unroll
      for (int o = 1; o < 16; o <<= 1) {
        pl += __shfl_xor(pl, o, 64);
        pr += __shfl_xor(pr, o, 64);
      }
      if (c == 0) {
        int nd = n0 + kg * 4 + reg;
        el[nd * 4 + hd] = pl;
        er[nd * 4 + hd] = pr;
      }
    }
  }
}

// ---------- GAT: degree-sorted waves, bf16 f gather, chunk-of-8 MLP ----------
__global__ void k_gat(const unsigned* __restrict__ fb, const float* __restrict__ el,
                      const float* __restrict__ er, const int* __restrict__ row_ptr,
                      const int* __restrict__ csrc, const int* __restrict__ nperm,
                      const float* __restrict__ bias, const float* __restrict__ g,
                      const float* __restrict__ be, float* __restrict__ h,
                      unsigned* __restrict__ hbd,
                      const float* __restrict__ gw, const float* __restrict__ gb,
                      float* __restrict__ gate) {
  int lane = threadIdx.x & 63;
  int n = nperm[blockIdx.x * 4 + (threadIdx.x >> 6)];
  int e0 = row_ptr[n], e1 = row_ptr[n + 1];
  float4 ern = reinterpret_cast<const float4*>(er)[n];
  int hh = lane >> 5;  // this lane's heads: hh and hh+2
  float ernA = hh ? ern.y : ern.x;
  float ernB = hh ? ern.w : ern.z;

  float sA = 0.f, sB = 0.f;
  float aA0 = 0.f, aA1 = 0.f, aB0 = 0.f, aB1 = 0.f;
  const float4* el4 = reinterpret_cast<const float4*>(el);

  auto edge = [&](float4 ec, unsigned v0, unsigned v1) {
    float elA = hh ? ec.y : ec.x;
    float elB = hh ? ec.w : ec.z;
    float w, pA, pB;
    w = elA + ernA; w = fmaxf(w, 0.2f * w); pA = __expf(w); sA += pA;
    w = elB + ernB; w = fmaxf(w, 0.2f * w); pB = __expf(w); sB += pB;
    aA0 = fmaf(__uint_as_float(v0 << 16), pA, aA0);
    aA1 = fmaf(__uint_as_float(v0 & 0xffff0000u), pA, aA1);
    aB0 = fmaf(__uint_as_float(v1 << 16), pB, aB0);
    aB1 = fmaf(__uint_as_float(v1 & 0xffff0000u), pB, aB1);
  };

  int t = e0;
  // chunk-of-8: 8 uniform csrc loads, then 24 independent gathers, then compute
  for (; t + 8 <= e1; t += 8) {
    int s0 = csrc[t],     s1 = csrc[t + 1], s2 = csrc[t + 2], s3 = csrc[t + 3];
    int s4 = csrc[t + 4], s5 = csrc[t + 5], s6 = csrc[t + 6], s7 = csrc[t + 7];
    float4 ea = el4[s0], eb_ = el4[s1], ec = el4[s2], ed = el4[s3];
    float4 ee = el4[s4], ef = el4[s5], eg_ = el4[s6], eh = el4[s7];
    unsigned a0 = fb[(size_t)s0 * 128 + lane], a1 = fb[(size_t)s0 * 128 + 64 + lane];
    unsigned b0 = fb[(size_t)s1 * 128 + lane], b1 = fb[(size_t)s1 * 128 + 64 + lane];
    unsigned c0 = fb[(size_t)s2 * 128 + lane], c1 = fb[(size_t)s2 * 128 + 64 + lane];
    unsigned d0 = fb[(size_t)s3 * 128 + lane], d1 = fb[(size_t)s3 * 128 + 64 + lane];
    unsigned e0_ = fb[(size_t)s4 * 128 + lane], e1_ = fb[(size_t)s4 * 128 + 64 + lane];
    unsigned f0 = fb[(size_t)s5 * 128 + lane], f1 = fb[(size_t)s5 * 128 + 64 + lane];
    unsigned g0 = fb[(size_t)s6 * 128 + lane], g1 = fb[(size_t)s6 * 128 + 64 + lane];
    unsigned h0 = fb[(size_t)s7 * 128 + lane], h1 = fb[(size_t)s7 * 128 + 64 + lane];
    edge(ea, a0, a1);
    edge(eb_, b0, b1);
    edge(ec, c0, c1);
    edge(ed, d0, d1);
    edge(ee, e0_, e1_);
    edge(ef, f0, f1);
    edge(eg_, g0, g1);
    edge(eh, h0, h1);
  }
  for (; t + 4 <= e1; t += 4) {
    int s0 = csrc[t], s1 = csrc[t + 1], s2 = csrc[t + 2], s3 = csrc[t + 3];
    float4 ea = el4[s0], eb_ = el4[s1], ec = el4[s2], ed = el4[s3];
    unsigned a0 = fb[(size_t)s0 * 128 + lane], a1 = fb[(size_t)s0 * 128 + 64 + lane];
    unsigned b0 = fb[(size_t)s1 * 128 + lane], b1 = fb[(size_t)s1 * 128 + 64 + lane];
    unsigned c0 = fb[(size_t)s2 * 128 + lane], c1 = fb[(size_t)s2 * 128 + 64 + lane];
    unsigned d0 = fb[(size_t)s3 * 128 + lane], d1 = fb[(size_t)s3 * 128 + 64 + lane];
    edge(ea, a0, a1);
    edge(eb_, b0, b1);
    edge(ec, c0, c1);
    edge(ed, d0, d1);
  }
  for (; t < e1; ++t) {
    int s0 = csrc[t];
    float4 ea = el4[s0];
    unsigned a0 = fb[(size_t)s0 * 128 + lane], a1 = fb[(size_t)s0 * 128 + 64 + lane];
    edge(ea, a0, a1);
  }

  float iA = sA > 0.f ? 1.f / sA : 0.f;
  float iB = sB > 0.f ? 1.f / sB : 0.f;
  int c0i = 2 * lane, c2i = 128 + 2 * lane;
  float2 bb0 = *reinterpret_cast<const float2*>(bias + c0i);
  float2 bb2 = *reinterpret_cast<const float2*>(bias + c2i);
  float y0 = fmaxf(aA0 * iA + bb0.x, 0.f);
  float y1 = fmaxf(aA1 * iA + bb0.y, 0.f);
  float y2 = fmaxf(aB0 * iB + bb2.x, 0.f);
  float y3 = fmaxf(aB1 * iB + bb2.y, 0.f);
  float s = y0 + y1 + y2 + y3;
  float q = y0 * y0 + y1 * y1 + y2 * y2 + y3 * y3;
  s = wave_sum(s); q = wave_sum(q);
  float mu = s * (1.f / HID);
  float rs = rsqrtf(fmaxf(q * (1.f / HID) - mu * mu, 0.f) + 1e-5f);
  float2 gg0 = *reinterpret_cast<const float2*>(g + c0i);
  float2 gg2 = *reinterpret_cast<const float2*>(g + c2i);
  float2 ee0 = *reinterpret_cast<const float2*>(be + c0i);
  float2 ee2 = *reinterpret_cast<const float2*>(be + c2i);
  float h0 = (y0 - mu) * rs * gg0.x + ee0.x;
  float h1 = (y1 - mu) * rs * gg0.y + ee0.y;
  float h2 = (y2 - mu) * rs * gg2.x + ee2.x;
  float h3 = (y3 - mu) * rs * gg2.y + ee2.y;
  size_t base = (size_t)n * HID;
  *reinterpret_cast<float2*>(h + base + c0i) = make_float2(h0, h1);
  *reinterpret_cast<float2*>(h + base + c2i) = make_float2(h2, h3);

  if (hbd) {  // bf16 pack for next layer's MFMA GEMM (pair-adjacent already)
    hbd[(size_t)n * 128 + lane] = f2bf(h0) | (f2bf(h1) << 16);
    hbd[(size_t)n * 128 + 64 + lane] = f2bf(h2) | (f2bf(h3) << 16);
  }
  if (gw) {  // fused gate score (layer 1 only)
    float2 w0 = *reinterpret_cast<const float2*>(gw + c0i);
    float2 w2 = *reinterpret_cast<const float2*>(gw + c2i);
    float p = h0 * w0.x + h1 * w0.y + h2 * w2.x + h3 * w2.y;
    p = wave_sum(p);
    if (lane == 0) gate[n] = p + gb[0];
  }
}

// ---------- per-graph max of gate ----------
__global__ void k_gmax(const float* __restrict__ gate, const int* __restrict__ gid,
                       unsigned* __restrict__ gmax_u) {
  __shared__ unsigned sm[NB];
  int t = threadIdx.x;
  if (t < NB) sm[t] = 0u;
  __syncthreads();
  int n = blockIdx.x * blockDim.x + t;
  if (n < N_FACES) atomicMax(&sm[gid[n]], enc_ord(gate[n]));
  __syncthreads();
  if (t < NB && sm[t] != 0u) atomicMax(&gmax_u[t], sm[t]);
}

// ---------- parallel weighted pooling (unnormalized, 1-ahead prefetch) ----------
#define PCHUNK 125
__global__ void k_psum(const float* __restrict__ h, const float* __restrict__ gate,
                       const int* __restrict__ gid, const unsigned* __restrict__ gmax_u,
                       float* __restrict__ praw, float* __restrict__ gs) {
  int t = threadIdx.x;
  int n0 = blockIdx.x * PCHUNK;
  int n1 = n0 + PCHUNK;
  if (n1 > N_FACES) n1 = N_FACES;
  if (n0 >= N_FACES) return;
  int cur = gid[n0];
  float gm = dec_ord(gmax_u[cur]);
  float acc = 0.f, wsum = 0.f;
  float hc = h[(size_t)n0 * HID + t];
  float gc = gate[n0];
  for (int n = n0; n < n1; ++n) {
    float hnext = 0.f, gnext = 0.f;
    if (n + 1 < n1) {
      hnext = h[(size_t)(n + 1) * HID + t];
      gnext = gate[n + 1];
    }
    int g = gid[n];
    if (g != cur) {
      atomicAdd(&praw[cur * HID + t], acc);
      if (t == 0) atomicAdd(&gs[cur], wsum);
      acc = 0.f; wsum = 0.f; cur = g; gm = dec_ord(gmax_u[cur]);
    }
    float w = __expf(gc - gm);
    acc += w * hc;
    wsum += w;
    hc = hnext; gc = gnext;
  }
  atomicAdd(&praw[cur * HID + t], acc);
  if (t == 0) atomicAdd(&gs[cur], wsum);
}

__global__ void k_poolnorm(const float* __restrict__ praw, const float* __restrict__ gs,
                           float* __restrict__ pooled) {
  int b = blockIdx.x, c = threadIdx.x;
  pooled[b * HID + c] = praw[b * HID + c] / gs[b];
}

// ---------- output projection + LN ----------
__global__ void k_out(const float* __restrict__ pooled, const float* __restrict__ oW,
                      const float* __restrict__ oB, const float* __restrict__ oG,
                      const float* __restrict__ oBe, float* __restrict__ feat) {
  int b = blockIdx.x;
  int o = threadIdx.x;  // 512 threads
  int lane = o & 63, wid = o >> 6;
  __shared__ float p[HID];
  __shared__ float partS[8], partQ[8];
  __shared__ float shMu, shRs;
  if (o < HID) p[o] = pooled[b * HID + o];
  __syncthreads();
  float a = oB[o];
  for (int k = 0; k < HID; ++k) a += p[k] * oW[k * NOUT + o];
  float y = fmaxf(a, 0.f);
  float s = wave_sum(y), q = wave_sum(y * y);
  if (lane == 0) { partS[wid] = s; partQ[wid] = q; }
  __syncthreads();
  if (o == 0) {
    float S = 0.f, Q = 0.f;
#pragma unroll
    for (int i = 0; i < 8; ++i) { S += partS[i]; Q += partQ[i]; }
    float mu = S * (1.f / NOUT);
    shMu = mu;
    shRs = rsqrtf(fmaxf(Q * (1.f / NOUT) - mu * mu, 0.f) + 1e-5f);
  }
  __syncthreads();
  feat[b * NOUT + o] = (y - shMu) * shRs * oG[o] + oBe[o];
}

extern "C" void kernel_launch(void* const* d_in, const int* in_sizes, int n_in,
                              void* d_out, int out_size, void* d_ws, size_t ws_size,
                              hipStream_t stream) {
  (void)in_sizes; (void)n_in; (void)out_size; (void)ws_size;
  const float* x_face    = (const float*)d_in[0];
  const float* x_edge    = (const float*)d_in[1];
  const float* face_W    = (const float*)d_in[2];
  const float* face_b    = (const float*)d_in[3];
  const float* face_g    = (const float*)d_in[4];
  const float* face_beta = (const float*)d_in[5];
  const float* edge_W    = (const float*)d_in[6];
  const float* edge_b    = (const float*)d_in[7];
  const float* edge_g    = (const float*)d_in[8];
  const float* edge_beta = (const float*)d_in[9];
  const float* g0_W      = (const float*)d_in[10];
  const float* g0_al     = (const float*)d_in[11];
  const float* g0_ar     = (const float*)d_in[12];
  const float* g0_bias   = (const float*)d_in[13];
  const float* g0_g      = (const float*)d_in[14];
  const float* g0_beta   = (const float*)d_in[15];
  const float* g1_W      = (const float*)d_in[16];
  const float* g1_al     = (const float*)d_in[17];
  const float* g1_ar     = (const float*)d_in[18];
  const float* g1_bias   = (const float*)d_in[19];
  const float* g1_g      = (const float*)d_in[20];
  const float* g1_beta   = (const float*)d_in[21];
  const float* gate_W    = (const float*)d_in[22];
  const float* gate_b    = (const float*)d_in[23];
  const float* out_W     = (const float*)d_in[24];
  const float* out_b     = (const float*)d_in[25];
  const float* out_g     = (const float*)d_in[26];
  const float* out_beta  = (const float*)d_in[27];
  const int*   src       = (const int*)d_in[28];
  const int*   dst       = (const int*)d_in[29];
  const int*   gid       = (const int*)d_in[30];

  char* ws = (char*)d_ws;
  size_t off = 0;
  auto take = [&](size_t bytes) -> char* {
    char* pp = ws + off;
    off += (bytes + 255) & ~(size_t)255;
    return pp;
  };
  int*      cnt      = (int*)take((size_t)N_FACES * 4);
  int*      fill     = (int*)take((size_t)N_FACES * 4);
  int*      row_ptr  = (int*)take((size_t)(N_FACES + 1) * 4);
  int*      bsum     = (int*)take((size_t)SCAN_NB * 4);
  int*      dbin     = (int*)take(64 * 4);
  int*      nperm    = (int*)take((size_t)N_FACES * 4);
  int*      csr_src  = (int*)take((size_t)N_EDGES * 4);
  int*      eid      = (int*)take((size_t)N_EDGES * 4);
  uint4*    rec16    = (uint4*)take((size_t)N_EDGES * 16);
  uint4*    Wp0      = (uint4*)take((size_t)8192 * 16);
  uint4*    Wp1      = (uint4*)take((size_t)8192 * 16);
  unsigned* gmax_u   = (unsigned*)take(64);
  float*    gs       = (float*)take(64);
  float*    praw     = (float*)take((size_t)NB * HID * 4);
  float*    el       = (float*)take((size_t)N_FACES * 4 * 4);
  float*    er       = (float*)take((size_t)N_FACES * 4 * 4);
  float*    gate     = (float*)take((size_t)N_FACES * 4);
  unsigned* fbuf     = (unsigned*)take((size_t)N_FACES * 128 * 4);
  unsigned* hbd      = (unsigned*)take((size_t)N_FACES * 128 * 4);

  float* outp   = (float*)d_out;
  float* feat   = outp;
  float* h      = outp + NB * NOUT;
  float* pooled = outp + NB * NOUT + (size_t)N_FACES * HID;

  hipMemsetAsync(cnt, 0, (size_t)N_FACES * 4, stream);
  hipMemsetAsync(fill, 0, (size_t)N_FACES * 4, stream);
  hipMemsetAsync(dbin, 0, 64 * 4, stream);
  hipMemsetAsync(gmax_u, 0, 64, stream);
  hipMemsetAsync(gs, 0, 64, stream);
  hipMemsetAsync(praw, 0, (size_t)NB * HID * 4, stream);

  k_hist<<<(N_EDGES + 255) / 256, 256, 0, stream>>>(dst, cnt);
  k_scan1<<<SCAN_NB, SCAN_B, 0, stream>>>(cnt, bsum);
  k_scan2<<<1, 64, 0, stream>>>(bsum);
  k_scan3<<<SCAN_NB, SCAN_B, 0, stream>>>(cnt, bsum, row_ptr);
  // degree counting-sort -> nperm (LDS-preaggregated)
  k_dhist<<<(N_FACES + 255) / 256, 256, 0, stream>>>(cnt, dbin);
  k_dscan<<<1, 64, 0, stream>>>(dbin);
  k_dscatter<<<(N_FACES + 255) / 256, 256, 0, stream>>>(cnt, dbin, nperm);
  k_packW<<<32, 256, 0, stream>>>(g0_W, Wp0);
  k_packW<<<32, 256, 0, stream>>>(g1_W, Wp1);
  k_scatter<<<N_EDGES / 64, 256, 0, stream>>>(dst, src, x_edge, row_ptr,
                                              edge_W, edge_b, fill, rec16,
                                              csr_src, eid);

  k_encode<<<N_FACES / 4, 256, 0, stream>>>(x_face, rec16, face_W, face_b, face_g, face_beta,
                                            edge_W, edge_b, edge_g, edge_beta,
                                            row_ptr, nperm, eid, h, hbd);
  // GAT layer 0
  k_gemm_mfma<<<(NT + 3) / 4, 256, 0, stream>>>(hbd, Wp0, g0_al, g0_ar, fbuf, el, er);
  k_gat<<<N_FACES / 4, 256, 0, stream>>>(fbuf, el, er, row_ptr, csr_src, nperm,
                                         g0_bias, g0_g, g0_beta, h, hbd,
                                         nullptr, nullptr, nullptr);
  // GAT layer 1 (+ fused gate scores)
  k_gemm_mfma<<<(NT + 3) / 4, 256, 0, stream>>>(hbd, Wp1, g1_al, g1_ar, fbuf, el, er);
  k_gat<<<N_FACES / 4, 256, 0, stream>>>(fbuf, el, er, row_ptr, csr_src, nperm,
                                         g1_bias, g1_g, g1_beta, h, nullptr,
                                         gate_W, gate_b, gate);
  // pooling + output head
  k_gmax<<<(N_FACES + 255) / 256, 256, 0, stream>>>(gate, gid, gmax_u);
  k_psum<<<(N_FACES + PCHUNK - 1) / PCHUNK, 256, 0, stream>>>(h, gate, gid, gmax_u, praw, gs);
  k_poolnorm<<<NB, HID, 0, stream>>>(praw, gs, pooled);
  k_out<<<NB, NOUT, 0, stream>>>(pooled, out_W, out_b, out_g, out_beta, feat);
}

// Round 17
// 476.200 us; speedup vs baseline: 1.0522x; 1.0522x over previous
//
#include <hip/hip_runtime.h>

#define N_FACES 50000
#define N_EDGES 800000
#define NB      16
#define HID     256
#define NOUT    512
#define SCAN_B  1024
#define SCAN_NB ((N_FACES + SCAN_B - 1) / SCAN_B)
#define NT      (N_FACES / 16)   // 3125 MFMA node-tiles (exact)

typedef __attribute__((ext_vector_type(8))) short short8v;
typedef __attribute__((ext_vector_type(4))) float float4v;
union U8 { uint4 u; short8v s; };

// ---------- wave helpers ----------
__device__ __forceinline__ float wave_sum(float v) {
#pragma unroll
  for (int o = 32; o; o >>= 1) v += __shfl_xor(v, o, 64);
  return v;
}

// ---------- order-preserving float<->uint encoding (for atomicMax) ----------
__device__ __forceinline__ unsigned enc_ord(float v) {
  unsigned b = __float_as_uint(v);
  return (b & 0x80000000u) ? ~b : (b | 0x80000000u);
}
__device__ __forceinline__ float dec_ord(unsigned e) {
  unsigned b = (e & 0x80000000u) ? (e ^ 0x80000000u) : ~e;
  return __uint_as_float(b);
}

// RNE float->bf16 (finite inputs)
__device__ __forceinline__ unsigned f2bf(float x) {
  unsigned u = __float_as_uint(x);
  return (u + 0x7fffu + ((u >> 16) & 1u)) >> 16;
}
__device__ __forceinline__ float bf_lo(unsigned u) { return __uint_as_float(u << 16); }
__device__ __forceinline__ float bf_hi(unsigned u) { return __uint_as_float(u & 0xffff0000u); }

// packed-bf16 dot2: d = a.lo*b.lo + a.hi*b.hi + c  (HW v_dot2_f32_bf16 when available)
#if __has_builtin(__builtin_amdgcn_fdot2_f32_bf16)
typedef __attribute__((ext_vector_type(2))) __bf16 bf16x2v;
__device__ __forceinline__ float dot2bf(unsigned a, unsigned b, float c) {
  union { unsigned u; bf16x2v v; } ua, ub;
  ua.u = a; ub.u = b;
  return __builtin_amdgcn_fdot2_f32_bf16(ua.v, ub.v, c, false);
}
#else
__device__ __forceinline__ float dot2bf(unsigned a, unsigned b, float c) {
  return fmaf(bf_lo(a), bf_lo(b), fmaf(bf_hi(a), bf_hi(b), c));
}
#endif

// ---------- CSR build ----------
__global__ void k_hist(const int* __restrict__ dst, int* __restrict__ cnt) {
  int e = blockIdx.x * blockDim.x + threadIdx.x;
  if (e < N_EDGES) atomicAdd(&cnt[dst[e]], 1);
}

__global__ void k_scan1(const int* __restrict__ cnt, int* __restrict__ bsum) {
  __shared__ int sh[SCAN_B];
  int i = blockIdx.x * SCAN_B + threadIdx.x;
  sh[threadIdx.x] = (i < N_FACES) ? cnt[i] : 0;
  __syncthreads();
  for (int off = SCAN_B / 2; off; off >>= 1) {
    if (threadIdx.x < off) sh[threadIdx.x] += sh[threadIdx.x + off];
    __syncthreads();
  }
  if (threadIdx.x == 0) bsum[blockIdx.x] = sh[0];
}

__global__ void k_scan2(int* __restrict__ bsum) {  // nb <= 64, one wave
  int t = threadIdx.x;
  int v = (t < SCAN_NB) ? bsum[t] : 0;
  int inc = v;
#pragma unroll
  for (int off = 1; off < 64; off <<= 1) {
    int u = __shfl_up(inc, off, 64);
    if (t >= off) inc += u;
  }
  if (t < SCAN_NB) bsum[t] = inc - v;  // exclusive
}

__global__ void k_scan3(const int* __restrict__ cnt, const int* __restrict__ bsum,
                        int* __restrict__ row_ptr) {
  __shared__ int sh[SCAN_B];
  int i = blockIdx.x * SCAN_B + threadIdx.x;
  int v = (i < N_FACES) ? cnt[i] : 0;
  sh[threadIdx.x] = v;
  __syncthreads();
  for (int off = 1; off < SCAN_B; off <<= 1) {
    int x = (threadIdx.x >= off) ? sh[threadIdx.x - off] : 0;
    __syncthreads();
    sh[threadIdx.x] += x;
    __syncthreads();
  }
  if (i < N_FACES) row_ptr[i] = bsum[blockIdx.x] + sh[threadIdx.x] - v;
  if (i == 0) row_ptr[N_FACES] = N_EDGES;
}

// ---------- degree counting-sort -> nperm (LDS-preaggregated, low contention) ----------
__global__ void k_dhist(const int* __restrict__ cnt, int* __restrict__ dbin) {
  __shared__ int lh[64];
  int t = threadIdx.x;
  if (t < 64) lh[t] = 0;
  __syncthreads();
  int n = blockIdx.x * blockDim.x + t;
  if (n < N_FACES) atomicAdd(&lh[min(cnt[n], 63)], 1);
  __syncthreads();
  if (t < 64 && lh[t] > 0) atomicAdd(&dbin[t], lh[t]);
}
__global__ void k_dscan(int* __restrict__ dbin) {  // 64 threads, one wave
  int t = threadIdx.x;
  int v = dbin[t];
  int inc = v;
#pragma unroll
  for (int off = 1; off < 64; off <<= 1) {
    int u = __shfl_up(inc, off, 64);
    if (t >= off) inc += u;
  }
  dbin[t] = inc - v;  // exclusive base; reused as fill counter
}
__global__ void k_dscatter(const int* __restrict__ cnt, int* __restrict__ dbin,
                           int* __restrict__ nperm) {
  __shared__ int lh[64];
  __shared__ int lbase[64];
  int t = threadIdx.x;
  if (t < 64) lh[t] = 0;
  __syncthreads();
  int n = blockIdx.x * blockDim.x + t;
  int b = 0, lrank = 0;
  if (n < N_FACES) {
    b = min(cnt[n], 63);
    lrank = atomicAdd(&lh[b], 1);  // LDS atomic: fast intra-block rank
  }
  __syncthreads();
  if (t < 64 && lh[t] > 0) lbase[t] = atomicAdd(&dbin[t], lh[t]);  // 1 global atomic per bin per block
  __syncthreads();
  if (n < N_FACES) nperm[lbase[b] + lrank] = n;
}

// ---------- scatter: 4 lanes/edge; packed-bf16 LDS weights (half LDS traffic), CSR-ordered rec16 ----------
__global__ void k_scatter(const int* __restrict__ dst, const int* __restrict__ src,
                          const float* __restrict__ xe, const int* __restrict__ row_ptr,
                          const float* __restrict__ eW, const float* __restrict__ eB,
                          int* __restrict__ fill, uint4* __restrict__ rec16,
                          int* __restrict__ csr_src) {
  __shared__ unsigned swp[3][HID];  // bf16 k-pairs per column
  __shared__ float sb[HID];
  int t = threadIdx.x;
  for (int i = t; i < 3 * HID; i += 256) {
    int kk = i / HID, c = i % HID;
    swp[kk][c] = f2bf(eW[(2 * kk) * HID + c]) | (f2bf(eW[(2 * kk + 1) * HID + c]) << 16);
  }
  for (int i = t; i < HID; i += 256) sb[i] = eB[i];
  __syncthreads();

  int e = blockIdx.x * 64 + (t >> 2);   // grid sized exactly: 12500 blocks
  int seg = t & 3;
  unsigned zb[6];
#pragma unroll
  for (int k = 0; k < 6; ++k) zb[k] = f2bf(xe[(size_t)e * 6 + k]);
  unsigned zp0 = zb[0] | (zb[1] << 16);
  unsigned zp1 = zb[2] | (zb[3] << 16);
  unsigned zp2 = zb[4] | (zb[5] << 16);

  int pos = 0;
  if (seg == 0) {
    int d = dst[e];
    int p = atomicAdd(&fill[d], 1);
    pos = row_ptr[d] + p;
  }
  pos = __shfl(pos, (t & 63) & ~3, 64);

  float s1 = 0.f, s2 = 0.f;
  int cbase = seg * 64;
  int rot = 4 * seg;  // rotate start so the 4 segs hit distinct banks (4i+4s mod 32)
#pragma unroll 4
  for (int ii = 0; ii < 16; ++ii) {
    int c = cbase + ((4 * ii + rot) & 63);
    float4 b4 = *reinterpret_cast<const float4*>(&sb[c]);
    uint4 w0 = *reinterpret_cast<const uint4*>(&swp[0][c]);
    uint4 w1 = *reinterpret_cast<const uint4*>(&swp[1][c]);
    uint4 w2 = *reinterpret_cast<const uint4*>(&swp[2][c]);
    float a0 = dot2bf(zp2, w2.x, dot2bf(zp1, w1.x, dot2bf(zp0, w0.x, b4.x)));
    float a1 = dot2bf(zp2, w2.y, dot2bf(zp1, w1.y, dot2bf(zp0, w0.y, b4.y)));
    float a2 = dot2bf(zp2, w2.z, dot2bf(zp1, w1.z, dot2bf(zp0, w0.z, b4.z)));
    float a3 = dot2bf(zp2, w2.w, dot2bf(zp1, w1.w, dot2bf(zp0, w0.w, b4.w)));
    a0 = fmaxf(a0, 0.f); a1 = fmaxf(a1, 0.f);
    a2 = fmaxf(a2, 0.f); a3 = fmaxf(a3, 0.f);
    s1 += (a0 + a1) + (a2 + a3);
    s2 += (a0 * a0 + a1 * a1) + (a2 * a2 + a3 * a3);
  }
  s1 += __shfl_xor(s1, 1, 64); s1 += __shfl_xor(s1, 2, 64);
  s2 += __shfl_xor(s2, 1, 64); s2 += __shfl_xor(s2, 2, 64);
  if (seg == 0) {
    float mu = s1 * (1.f / HID);
    float rs = rsqrtf(fmaxf(s2 * (1.f / HID) - mu * mu, 0.f) + 1e-5f);
    csr_src[pos] = src[e];
    rec16[pos] = make_uint4(zp0, zp1, zp2, f2bf(mu) | (f2bf(rs) << 16));
  }
}

// ---------- encoders + mean aggregation (chunk-of-2 edges; dot2 bf16; folded LN) ----------
__global__ void k_encode(const float* __restrict__ xf, const uint4* __restrict__ rec16,
                         const float* __restrict__ fW, const float* __restrict__ fB,
                         const float* __restrict__ fG, const float* __restrict__ fBe,
                         const float* __restrict__ eW, const float* __restrict__ eB,
                         const float* __restrict__ eG, const float* __restrict__ eBe,
                         const int* __restrict__ row_ptr, const int* __restrict__ nperm,
                         float* __restrict__ h, unsigned* __restrict__ hbd) {
  int lane = threadIdx.x & 63;
  int n = nperm[blockIdx.x * 4 + (threadIdx.x >> 6)];

  // face encoder
  float x[7];
#pragma unroll
  for (int k = 0; k < 7; ++k) x[k] = xf[n * 7 + k];
  float y[4];
#pragma unroll
  for (int j = 0; j < 4; ++j) {
    int c = lane + 64 * j;
    float a = fB[c];
#pragma unroll
    for (int k = 0; k < 7; ++k) a += x[k] * fW[k * HID + c];
    y[j] = fmaxf(a, 0.f);
  }
  float s = y[0] + y[1] + y[2] + y[3];
  float s2 = y[0] * y[0] + y[1] * y[1] + y[2] * y[2] + y[3] * y[3];
  s = wave_sum(s); s2 = wave_sum(s2);
  float mu = s * (1.f / HID);
  float rs = rsqrtf(fmaxf(s2 * (1.f / HID) - mu * mu, 0.f) + 1e-5f);
  float hv[4];
#pragma unroll
  for (int j = 0; j < 4; ++j) {
    int c = lane + 64 * j;
    hv[j] = (y[j] - mu) * rs * fG[c] + fBe[c];
  }

  // hoist edge-encoder params; pack weights as bf16 k-pairs for dot2
  unsigned ewp[3][4];
  float eb[4], eg[4], ebe[4];
#pragma unroll
  for (int j = 0; j < 4; ++j) {
    int c = lane + 64 * j;
    eb[j] = eB[c]; eg[j] = eG[c]; ebe[j] = eBe[c];
#pragma unroll
    for (int kk = 0; kk < 3; ++kk)
      ewp[kk][j] = f2bf(eW[(2 * kk) * HID + c]) | (f2bf(eW[(2 * kk + 1) * HID + c]) << 16);
  }

  int e0 = row_ptr[n], e1 = row_ptr[n + 1];
  // folded LN: acc[j] = Σ relu(a)·rs ; smu = Σ μ·rs ; apply eg/ebe once at end
  float acc[4] = {0.f, 0.f, 0.f, 0.f};
  float smu = 0.f;
  int t = e0;
  // chunk-of-2: two independent record loads per iteration (sequential, coalesced)
  for (; t + 2 <= e1; t += 2) {
    uint4 cu = rec16[t];
    uint4 cv = rec16[t + 1];
    float emu0 = bf_lo(cu.w), ers0 = bf_hi(cu.w);
    float emu1 = bf_lo(cv.w), ers1 = bf_hi(cv.w);
    smu = fmaf(emu0, ers0, smu);
    smu = fmaf(emu1, ers1, smu);
#pragma unroll
    for (int j = 0; j < 4; ++j) {
      float a = dot2bf(cu.x, ewp[0][j], eb[j]);
      a = dot2bf(cu.y, ewp[1][j], a);
      a = dot2bf(cu.z, ewp[2][j], a);
      a = fmaxf(a, 0.f);
      acc[j] = fmaf(a, ers0, acc[j]);
      float b = dot2bf(cv.x, ewp[0][j], eb[j]);
      b = dot2bf(cv.y, ewp[1][j], b);
      b = dot2bf(cv.z, ewp[2][j], b);
      b = fmaxf(b, 0.f);
      acc[j] = fmaf(b, ers1, acc[j]);
    }
  }
  for (; t < e1; ++t) {
    uint4 cu = rec16[t];
    float emu0 = bf_lo(cu.w), ers0 = bf_hi(cu.w);
    smu = fmaf(emu0, ers0, smu);
#pragma unroll
    for (int j = 0; j < 4; ++j) {
      float a = dot2bf(cu.x, ewp[0][j], eb[j]);
      a = dot2bf(cu.y, ewp[1][j], a);
      a = dot2bf(cu.z, ewp[2][j], a);
      a = fmaxf(a, 0.f);
      acc[j] = fmaf(a, ers0, acc[j]);
    }
  }
  int cntE = e1 - e0;
  float inv = (cntE > 0) ? 1.f / (float)cntE : 0.f;
  float hval[4];
#pragma unroll
  for (int j = 0; j < 4; ++j) {
    float add = (cntE > 0) ? inv * eg[j] * (acc[j] - smu) + ebe[j] : 0.f;
    hval[j] = hv[j] + add;
    h[(size_t)n * HID + lane + 64 * j] = hval[j];
  }
  // packed bf16 h: dword idx = global_col/2; lane l owns cols l+64j, partner l^1
#pragma unroll
  for (int j = 0; j < 4; ++j) {
    float other = __shfl_xor(hval[j], 1, 64);
    if (!(lane & 1))
      hbd[(size_t)n * 128 + 32 * j + (lane >> 1)] = f2bf(hval[j]) | (f2bf(other) << 16);
  }
}

// ---------- pack W (fp32 [K][256]) into MFMA B-fragment layout (bf16) ----------
__global__ void k_packW(const float* __restrict__ W, uint4* __restrict__ Wp) {
  int i = blockIdx.x * 256 + threadIdx.x;  // 16ct * 8ks * 64lane = 8192
  int lane = i & 63, ks = (i >> 6) & 7, ct = i >> 9;
  int kbase = ks * 32 + (lane >> 4) * 8;
  int col = ct * 16 + (lane & 15);
  unsigned d[4];
#pragma unroll
  for (int r = 0; r < 4; ++r) {
    unsigned lo = f2bf(W[(size_t)(kbase + 2 * r) * HID + col]);
    unsigned hi = f2bf(W[(size_t)(kbase + 2 * r + 1) * HID + col]);
    d[r] = lo | (hi << 16);
  }
  Wp[i] = make_uint4(d[0], d[1], d[2], d[3]);
}

// ---------- MFMA GEMM: f=h@W (bf16), fused el/er + fb-layout write ----------
__global__ void k_gemm_mfma(const unsigned* __restrict__ hbd, const uint4* __restrict__ Wp,
                            const float* __restrict__ al, const float* __restrict__ ar,
                            unsigned* __restrict__ fb, float* __restrict__ el,
                            float* __restrict__ er) {
  int tile = blockIdx.x * 4 + (threadIdx.x >> 6);
  if (tile >= NT) return;
  int lane = threadIdx.x & 63;
  int c = lane & 15;   // A-row / B,D-col within tile
  int kg = lane >> 4;  // k-group
  int n0 = tile * 16;

  uint4 afrag[8];
#pragma unroll
  for (int ks = 0; ks < 8; ++ks)
    afrag[ks] = *reinterpret_cast<const uint4*>(hbd + (size_t)(n0 + c) * 128 + ks * 16 + kg * 4);

  float4v acc[16];
#pragma unroll
  for (int ct = 0; ct < 16; ++ct) acc[ct] = (float4v){0.f, 0.f, 0.f, 0.f};
#pragma unroll
  for (int ct = 0; ct < 16; ++ct) {
#pragma unroll
    for (int ks = 0; ks < 8; ++ks) {
      U8 a, b;
      a.u = afrag[ks];
      b.u = Wp[(ct * 8 + ks) * 64 + lane];
      acc[ct] = __builtin_amdgcn_mfma_f32_16x16x32_bf16(a.s, b.s, acc[ct], 0, 0, 0);
    }
  }

  // fb write (k_gat layout: dword = global_col/2): pack pair via shfl_xor(1)
#pragma unroll
  for (int ct = 0; ct < 16; ++ct) {
#pragma unroll
    for (int reg = 0; reg < 4; ++reg) {
      float v = acc[ct][reg];
      float vo = __shfl_xor(v, 1, 64);
      if (!(lane & 1)) {
        int nd = n0 + kg * 4 + reg;
        fb[(size_t)nd * 128 + ct * 8 + (c >> 1)] = f2bf(v) | (f2bf(vo) << 16);
      }
    }
  }

  // el/er: reduce over 16 cols per tile-col-group; head = ct>>2
  float alr[16], arr[16];
#pragma unroll
  for (int ct = 0; ct < 16; ++ct) {
    alr[ct] = al[ct * 16 + c];
    arr[ct] = ar[ct * 16 + c];
  }
#pragma unroll
  for (int hd = 0; hd < 4; ++hd) {
#pragma unroll
    for (int reg = 0; reg < 4; ++reg) {
      float pl = 0.f, pr = 0.f;
#pragma unroll
      for (int q = 0; q < 4; ++q) {
        int ct = hd * 4 + q;
        pl = fmaf(acc[ct][reg], alr[ct], pl);
        pr = fmaf(acc[ct][reg], arr[ct], pr);
      }
#pragma unroll
      for (int o = 1; o < 16; o <<= 1) {
        pl += __shfl_xor(pl, o, 64);
        pr += __shfl_xor(pr, o, 64);
      }
      if (c == 0) {
        int nd = n0 + kg * 4 + reg;
        el[nd * 4 + hd] = pl;
        er[nd * 4 + hd] = pr;
      }
    }
  }
}

// ---------- GAT: degree-sorted waves, bf16 f gather, chunk-of-8 MLP ----------
__global__ void k_gat(const unsigned* __restrict__ fb, const float* __restrict__ el,
                      const float* __restrict__ er, const int* __restrict__ row_ptr,
                      const int* __restrict__ csrc, const int* __restrict__ nperm,
                      const float* __restrict__ bias, const float* __restrict__ g,
                      const float* __restrict__ be, float* __restrict__ h,
                      unsigned* __restrict__ hbd,
                      const float* __restrict__ gw, const float* __restrict__ gb,
                      float* __restrict__ gate) {
  int lane = threadIdx.x & 63;
  int n = nperm[blockIdx.x * 4 + (threadIdx.x >> 6)];
  int e0 = row_ptr[n], e1 = row_ptr[n + 1];
  float4 ern = reinterpret_cast<const float4*>(er)[n];
  int hh = lane >> 5;  // this lane's heads: hh and hh+2
  float ernA = hh ? ern.y : ern.x;
  float ernB = hh ? ern.w : ern.z;

  float sA = 0.f, sB = 0.f;
  float aA0 = 0.f, aA1 = 0.f, aB0 = 0.f, aB1 = 0.f;
  const float4* el4 = reinterpret_cast<const float4*>(el);

  auto edge = [&](float4 ec, unsigned v0, unsigned v1) {
    float elA = hh ? ec.y : ec.x;
    float elB = hh ? ec.w : ec.z;
    float w, pA, pB;
    w = elA + ernA; w = fmaxf(w, 0.2f * w); pA = __expf(w); sA += pA;
    w = elB + ernB; w = fmaxf(w, 0.2f * w); pB = __expf(w); sB += pB;
    aA0 = fmaf(__uint_as_float(v0 << 16), pA, aA0);
    aA1 = fmaf(__uint_as_float(v0 & 0xffff0000u), pA, aA1);
    aB0 = fmaf(__uint_as_float(v1 << 16), pB, aB0);
    aB1 = fmaf(__uint_as_float(v1 & 0xffff0000u), pB, aB1);
  };

  int t = e0;
  // chunk-of-8: 8 uniform csrc loads, then 24 independent gathers, then compute
  for (; t + 8 <= e1; t += 8) {
    int s0 = csrc[t],     s1 = csrc[t + 1], s2 = csrc[t + 2], s3 = csrc[t + 3];
    int s4 = csrc[t + 4], s5 = csrc[t + 5], s6 = csrc[t + 6], s7 = csrc[t + 7];
    float4 ea = el4[s0], eb_ = el4[s1], ec = el4[s2], ed = el4[s3];
    float4 ee = el4[s4], ef = el4[s5], eg_ = el4[s6], eh = el4[s7];
    unsigned a0 = fb[(size_t)s0 * 128 + lane], a1 = fb[(size_t)s0 * 128 + 64 + lane];
    unsigned b0 = fb[(size_t)s1 * 128 + lane], b1 = fb[(size_t)s1 * 128 + 64 + lane];
    unsigned c0 = fb[(size_t)s2 * 128 + lane], c1 = fb[(size_t)s2 * 128 + 64 + lane];
    unsigned d0 = fb[(size_t)s3 * 128 + lane], d1 = fb[(size_t)s3 * 128 + 64 + lane];
    unsigned e0_ = fb[(size_t)s4 * 128 + lane], e1_ = fb[(size_t)s4 * 128 + 64 + lane];
    unsigned f0 = fb[(size_t)s5 * 128 + lane], f1 = fb[(size_t)s5 * 128 + 64 + lane];
    unsigned g0 = fb[(size_t)s6 * 128 + lane], g1 = fb[(size_t)s6 * 128 + 64 + lane];
    unsigned h0 = fb[(size_t)s7 * 128 + lane], h1 = fb[(size_t)s7 * 128 + 64 + lane];
    edge(ea, a0, a1);
    edge(eb_, b0, b1);
    edge(ec, c0, c1);
    edge(ed, d0, d1);
    edge(ee, e0_, e1_);
    edge(ef, f0, f1);
    edge(eg_, g0, g1);
    edge(eh, h0, h1);
  }
  for (; t + 4 <= e1; t += 4) {
    int s0 = csrc[t], s1 = csrc[t + 1], s2 = csrc[t + 2], s3 = csrc[t + 3];
    float4 ea = el4[s0], eb_ = el4[s1], ec = el4[s2], ed = el4[s3];
    unsigned a0 = fb[(size_t)s0 * 128 + lane], a1 = fb[(size_t)s0 * 128 + 64 + lane];
    unsigned b0 = fb[(size_t)s1 * 128 + lane], b1 = fb[(size_t)s1 * 128 + 64 + lane];
    unsigned c0 = fb[(size_t)s2 * 128 + lane], c1 = fb[(size_t)s2 * 128 + 64 + lane];
    unsigned d0 = fb[(size_t)s3 * 128 + lane], d1 = fb[(size_t)s3 * 128 + 64 + lane];
    edge(ea, a0, a1);
    edge(eb_, b0, b1);
    edge(ec, c0, c1);
    edge(ed, d0, d1);
  }
  for (; t < e1; ++t) {
    int s0 = csrc[t];
    float4 ea = el4[s0];
    unsigned a0 = fb[(size_t)s0 * 128 + lane], a1 = fb[(size_t)s0 * 128 + 64 + lane];
    edge(ea, a0, a1);
  }

  float iA = sA > 0.f ? 1.f / sA : 0.f;
  float iB = sB > 0.f ? 1.f / sB : 0.f;
  int c0i = 2 * lane, c2i = 128 + 2 * lane;
  float2 bb0 = *reinterpret_cast<const float2*>(bias + c0i);
  float2 bb2 = *reinterpret_cast<const float2*>(bias + c2i);
  float y0 = fmaxf(aA0 * iA + bb0.x, 0.f);
  float y1 = fmaxf(aA1 * iA + bb0.y, 0.f);
  float y2 = fmaxf(aB0 * iB + bb2.x, 0.f);
  float y3 = fmaxf(aB1 * iB + bb2.y, 0.f);
  float s = y0 + y1 + y2 + y3;
  float q = y0 * y0 + y1 * y1 + y2 * y2 + y3 * y3;
  s = wave_sum(s); q = wave_sum(q);
  float mu = s * (1.f / HID);
  float rs = rsqrtf(fmaxf(q * (1.f / HID) - mu * mu, 0.f) + 1e-5f);
  float2 gg0 = *reinterpret_cast<const float2*>(g + c0i);
  float2 gg2 = *reinterpret_cast<const float2*>(g + c2i);
  float2 ee0 = *reinterpret_cast<const float2*>(be + c0i);
  float2 ee2 = *reinterpret_cast<const float2*>(be + c2i);
  float h0 = (y0 - mu) * rs * gg0.x + ee0.x;
  float h1 = (y1 - mu) * rs * gg0.y + ee0.y;
  float h2 = (y2 - mu) * rs * gg2.x + ee2.x;
  float h3 = (y3 - mu) * rs * gg2.y + ee2.y;
  size_t base = (size_t)n * HID;
  *reinterpret_cast<float2*>(h + base + c0i) = make_float2(h0, h1);
  *reinterpret_cast<float2*>(h + base + c2i) = make_float2(h2, h3);

  if (hbd) {  // bf16 pack for next layer's MFMA GEMM (pair-adjacent already)
    hbd[(size_t)n * 128 + lane] = f2bf(h0) | (f2bf(h1) << 16);
    hbd[(size_t)n * 128 + 64 + lane] = f2bf(h2) | (f2bf(h3) << 16);
  }
  if (gw) {  // fused gate score (layer 1 only)
    float2 w0 = *reinterpret_cast<const float2*>(gw + c0i);
    float2 w2 = *reinterpret_cast<const float2*>(gw + c2i);
    float p = h0 * w0.x + h1 * w0.y + h2 * w2.x + h3 * w2.y;
    p = wave_sum(p);
    if (lane == 0) gate[n] = p + gb[0];
  }
}

// ---------- per-graph max of gate ----------
__global__ void k_gmax(const float* __restrict__ gate, const int* __restrict__ gid,
                       unsigned* __restrict__ gmax_u) {
  __shared__ unsigned sm[NB];
  int t = threadIdx.x;
  if (t < NB) sm[t] = 0u;
  __syncthreads();
  int n = blockIdx.x * blockDim.x + t;
  if (n < N_FACES) atomicMax(&sm[gid[n]], enc_ord(gate[n]));
  __syncthreads();
  if (t < NB && sm[t] != 0u) atomicMax(&gmax_u[t], sm[t]);
}

// ---------- parallel weighted pooling (unnormalized, 1-ahead prefetch) ----------
#define PCHUNK 125
__global__ void k_psum(const float* __restrict__ h, const float* __restrict__ gate,
                       const int* __restrict__ gid, const unsigned* __restrict__ gmax_u,
                       float* __restrict__ praw, float* __restrict__ gs) {
  int t = threadIdx.x;
  int n0 = blockIdx.x * PCHUNK;
  int n1 = n0 + PCHUNK;
  if (n1 > N_FACES) n1 = N_FACES;
  if (n0 >= N_FACES) return;
  int cur = gid[n0];
  float gm = dec_ord(gmax_u[cur]);
  float acc = 0.f, wsum = 0.f;
  float hc = h[(size_t)n0 * HID + t];
  float gc = gate[n0];
  for (int n = n0; n < n1; ++n) {
    float hnext = 0.f, gnext = 0.f;
    if (n + 1 < n1) {
      hnext = h[(size_t)(n + 1) * HID + t];
      gnext = gate[n + 1];
    }
    int g = gid[n];
    if (g != cur) {
      atomicAdd(&praw[cur * HID + t], acc);
      if (t == 0) atomicAdd(&gs[cur], wsum);
      acc = 0.f; wsum = 0.f; cur = g; gm = dec_ord(gmax_u[cur]);
    }
    float w = __expf(gc - gm);
    acc += w * hc;
    wsum += w;
    hc = hnext; gc = gnext;
  }
  atomicAdd(&praw[cur * HID + t], acc);
  if (t == 0) atomicAdd(&gs[cur], wsum);
}

__global__ void k_poolnorm(const float* __restrict__ praw, const float* __restrict__ gs,
                           float* __restrict__ pooled) {
  int b = blockIdx.x, c = threadIdx.x;
  pooled[b * HID + c] = praw[b * HID + c] / gs[b];
}

// ---------- output projection + LN ----------
__global__ void k_out(const float* __restrict__ pooled, const float* __restrict__ oW,
                      const float* __restrict__ oB, const float* __restrict__ oG,
                      const float* __restrict__ oBe, float* __restrict__ feat) {
  int b = blockIdx.x;
  int o = threadIdx.x;  // 512 threads
  int lane = o & 63, wid = o >> 6;
  __shared__ float p[HID];
  __shared__ float partS[8], partQ[8];
  __shared__ float shMu, shRs;
  if (o < HID) p[o] = pooled[b * HID + o];
  __syncthreads();
  float a = oB[o];
  for (int k = 0; k < HID; ++k) a += p[k] * oW[k * NOUT + o];
  float y = fmaxf(a, 0.f);
  float s = wave_sum(y), q = wave_sum(y * y);
  if (lane == 0) { partS[wid] = s; partQ[wid] = q; }
  __syncthreads();
  if (o == 0) {
    float S = 0.f, Q = 0.f;
#pragma unroll
    for (int i = 0; i < 8; ++i) { S += partS[i]; Q += partQ[i]; }
    float mu = S * (1.f / NOUT);
    shMu = mu;
    shRs = rsqrtf(fmaxf(Q * (1.f / NOUT) - mu * mu, 0.f) + 1e-5f);
  }
  __syncthreads();
  feat[b * NOUT + o] = (y - shMu) * shRs * oG[o] + oBe[o];
}

extern "C" void kernel_launch(void* const* d_in, const int* in_sizes, int n_in,
                              void* d_out, int out_size, void* d_ws, size_t ws_size,
                              hipStream_t stream) {
  (void)in_sizes; (void)n_in; (void)out_size; (void)ws_size;
  const float* x_face    = (const float*)d_in[0];
  const float* x_edge    = (const float*)d_in[1];
  const float* face_W    = (const float*)d_in[2];
  const float* face_b    = (const float*)d_in[3];
  const float* face_g    = (const float*)d_in[4];
  const float* face_beta = (const float*)d_in[5];
  const float* edge_W    = (const float*)d_in[6];
  const float* edge_b    = (const float*)d_in[7];
  const float* edge_g    = (const float*)d_in[8];
  const float* edge_beta = (const float*)d_in[9];
  const float* g0_W      = (const float*)d_in[10];
  const float* g0_al     = (const float*)d_in[11];
  const float* g0_ar     = (const float*)d_in[12];
  const float* g0_bias   = (const float*)d_in[13];
  const float* g0_g      = (const float*)d_in[14];
  const float* g0_beta   = (const float*)d_in[15];
  const float* g1_W      = (const float*)d_in[16];
  const float* g1_al     = (const float*)d_in[17];
  const float* g1_ar     = (const float*)d_in[18];
  const float* g1_bias   = (const float*)d_in[19];
  const float* g1_g      = (const float*)d_in[20];
  const float* g1_beta   = (const float*)d_in[21];
  const float* gate_W    = (const float*)d_in[22];
  const float* gate_b    = (const float*)d_in[23];
  const float* out_W     = (const float*)d_in[24];
  const float* out_b     = (const float*)d_in[25];
  const float* out_g     = (const float*)d_in[26];
  const float* out_beta  = (const float*)d_in[27];
  const int*   src       = (const int*)d_in[28];
  const int*   dst       = (const int*)d_in[29];
  const int*   gid       = (const int*)d_in[30];

  char* ws = (char*)d_ws;
  size_t off = 0;
  auto take = [&](size_t bytes) -> char* {
    char* pp = ws + off;
    off += (bytes + 255) & ~(size_t)255;
    return pp;
  };
  int*      cnt      = (int*)take((size_t)N_FACES * 4);
  int*      fill     = (int*)take((size_t)N_FACES * 4);
  int*      row_ptr  = (int*)take((size_t)(N_FACES + 1) * 4);
  int*      bsum     = (int*)take((size_t)SCAN_NB * 4);
  int*      dbin     = (int*)take(64 * 4);
  int*      nperm    = (int*)take((size_t)N_FACES * 4);
  int*      csr_src  = (int*)take((size_t)N_EDGES * 4);
  uint4*    rec16    = (uint4*)take((size_t)N_EDGES * 16);
  uint4*    Wp0      = (uint4*)take((size_t)8192 * 16);
  uint4*    Wp1      = (uint4*)take((size_t)8192 * 16);
  unsigned* gmax_u   = (unsigned*)take(64);
  float*    gs       = (float*)take(64);
  float*    praw     = (float*)take((size_t)NB * HID * 4);
  float*    el       = (float*)take((size_t)N_FACES * 4 * 4);
  float*    er       = (float*)take((size_t)N_FACES * 4 * 4);
  float*    gate     = (float*)take((size_t)N_FACES * 4);
  unsigned* fbuf     = (unsigned*)take((size_t)N_FACES * 128 * 4);
  unsigned* hbd      = (unsigned*)take((size_t)N_FACES * 128 * 4);

  float* outp   = (float*)d_out;
  float* feat   = outp;
  float* h      = outp + NB * NOUT;
  float* pooled = outp + NB * NOUT + (size_t)N_FACES * HID;

  hipMemsetAsync(cnt, 0, (size_t)N_FACES * 4, stream);
  hipMemsetAsync(fill, 0, (size_t)N_FACES * 4, stream);
  hipMemsetAsync(dbin, 0, 64 * 4, stream);
  hipMemsetAsync(gmax_u, 0, 64, stream);
  hipMemsetAsync(gs, 0, 64, stream);
  hipMemsetAsync(praw, 0, (size_t)NB * HID * 4, stream);

  k_hist<<<(N_EDGES + 255) / 256, 256, 0, stream>>>(dst, cnt);
  k_scan1<<<SCAN_NB, SCAN_B, 0, stream>>>(cnt, bsum);
  k_scan2<<<1, 64, 0, stream>>>(bsum);
  k_scan3<<<SCAN_NB, SCAN_B, 0, stream>>>(cnt, bsum, row_ptr);
  // degree counting-sort -> nperm (LDS-preaggregated)
  k_dhist<<<(N_FACES + 255) / 256, 256, 0, stream>>>(cnt, dbin);
  k_dscan<<<1, 64, 0, stream>>>(dbin);
  k_dscatter<<<(N_FACES + 255) / 256, 256, 0, stream>>>(cnt, dbin, nperm);
  k_packW<<<32, 256, 0, stream>>>(g0_W, Wp0);
  k_packW<<<32, 256, 0, stream>>>(g1_W, Wp1);
  k_scatter<<<N_EDGES / 64, 256, 0, stream>>>(dst, src, x_edge, row_ptr,
                                              edge_W, edge_b, fill, rec16, csr_src);

  k_encode<<<N_FACES / 4, 256, 0, stream>>>(x_face, rec16, face_W, face_b, face_g, face_beta,
                                            edge_W, edge_b, edge_g, edge_beta,
                                            row_ptr, nperm, h, hbd);
  // GAT layer 0
  k_gemm_mfma<<<(NT + 3) / 4, 256, 0, stream>>>(hbd, Wp0, g0_al, g0_ar, fbuf, el, er);
  k_gat<<<N_FACES / 4, 256, 0, stream>>>(fbuf, el, er, row_ptr, csr_src, nperm,
                                         g0_bias, g0_g, g0_beta, h, hbd,
                                         nullptr, nullptr, nullptr);
  // GAT layer 1 (+ fused gate scores)
  k_gemm_mfma<<<(NT + 3) / 4, 256, 0, stream>>>(hbd, Wp1, g1_al, g1_ar, fbuf, el, er);
  k_gat<<<N_FACES / 4, 256, 0, stream>>>(fbuf, el, er, row_ptr, csr_src, nperm,
                                         g1_bias, g1_g, g1_beta, h, nullptr,
                                         gate_W, gate_b, gate);
  // pooling + output head
  k_gmax<<<(N_FACES + 255) / 256, 256, 0, stream>>>(gate, gid, gmax_u);
  k_psum<<<(N_FACES + PCHUNK - 1) / PCHUNK, 256, 0, stream>>>(h, gate, gid, gmax_u, praw, gs);
  k_poolnorm<<<NB, HID, 0, stream>>>(praw, gs, pooled);
  k_out<<<NB, NOUT, 0, stream>>>(pooled, out_W, out_b, out_g, out_beta, feat);
}